// Round 2
// baseline (20535.081 us; speedup 1.0000x reference)
//
#include <hip/hip_runtime.h>
#include <hip/hip_cooperative_groups.h>

namespace cg = cooperative_groups;

#define T_STEPS 512
#define NB 64
#define D_IN 1024
#define HID 1024
#define G4 4096
#define KTOT 2048

typedef short short8 __attribute__((ext_vector_type(8)));
typedef float f32x4 __attribute__((ext_vector_type(4)));

static __device__ __forceinline__ unsigned short f2bf(float f) {
    unsigned int u = __builtin_bit_cast(unsigned int, f);
    u += 0x7fffu + ((u >> 16) & 1u);
    return (unsigned short)(u >> 16);
}

// Build Wc bf16 [4096][2048]: cols 0..1023 = W_ih row, 1024..2047 = W_hh row.
__global__ void cvt_w_kernel(const float* __restrict__ wih, const float* __restrict__ whh,
                             unsigned short* __restrict__ wc) {
    size_t idx = ((size_t)blockIdx.x * blockDim.x + threadIdx.x) * 8;
    if (idx >= (size_t)G4 * KTOT) return;
    int k = (int)(idx & (KTOT - 1));
    int g = (int)(idx >> 11);
    const float* src = (k < D_IN) ? (wih + (size_t)g * D_IN + k)
                                  : (whh + (size_t)g * HID + (k - D_IN));
    float4 a = *(const float4*)src;
    float4 b = *(const float4*)(src + 4);
    short8 v;
    v[0] = (short)f2bf(a.x); v[1] = (short)f2bf(a.y);
    v[2] = (short)f2bf(a.z); v[3] = (short)f2bf(a.w);
    v[4] = (short)f2bf(b.x); v[5] = (short)f2bf(b.y);
    v[6] = (short)f2bf(b.z); v[7] = (short)f2bf(b.w);
    *(short8*)(wc + idx) = v;
}

// x (N,T,D) fp32 -> xb (T,N,D) bf16
__global__ void cvt_x_kernel(const float* __restrict__ x, unsigned short* __restrict__ xb) {
    size_t idx = ((size_t)blockIdx.x * blockDim.x + threadIdx.x) * 8;
    if (idx >= (size_t)NB * T_STEPS * D_IN) return;
    int d = (int)(idx & (D_IN - 1));
    size_t nt = idx >> 10;           // n*512 + t
    int t = (int)(nt & (T_STEPS - 1));
    int n = (int)(nt >> 9);
    float4 a = *(const float4*)(x + idx);
    float4 b = *(const float4*)(x + idx + 4);
    short8 v;
    v[0] = (short)f2bf(a.x); v[1] = (short)f2bf(a.y);
    v[2] = (short)f2bf(a.z); v[3] = (short)f2bf(a.w);
    v[4] = (short)f2bf(b.x); v[5] = (short)f2bf(b.y);
    v[6] = (short)f2bf(b.z); v[7] = (short)f2bf(b.w);
    *(short8*)(xb + (((size_t)t * NB + n) << 10) + d) = v;
}

__global__ void init_kernel(unsigned short* __restrict__ h0, float* __restrict__ c,
                            const float* __restrict__ bih, const float* __restrict__ bhh,
                            float* __restrict__ bias) {
    int i = blockIdx.x * blockDim.x + threadIdx.x;
    if (i < NB * HID) { h0[i] = 0; c[i] = 0.f; }
    if (i < G4) bias[i] = bih[i] + bhh[i];
}

// Persistent LSTM: 256 WGs x 512 threads, 1 WG/CU.
// WG wg: g = wg>>1 owns hidden units [g*8, g*8+8); bgrp = wg&1 owns batch [bgrp*32, +32).
// LDS holds the WG's 32 gate rows of Wc (local row lr = q*8+r -> global row q*1024+g*8+r),
// XOR-swizzled (byte ^= (lr&7)<<4) to break the stride-4096B column bank conflict.
// Waves 0-3: x-part (K 0..1023). Waves 4-7: h-part (K 1024..2047). Tile (mt,nt) = (w&1,(w>>1)&1).
__global__ __launch_bounds__(512, 1) void lstm_persist(
    const unsigned short* __restrict__ xb,   // [512][64][1024] bf16
    const unsigned short* __restrict__ wc,   // [4096][2048] bf16
    const float* __restrict__ bias,          // [4096]
    float* __restrict__ c,                   // [64][1024]
    unsigned short* __restrict__ h0,
    unsigned short* __restrict__ h1,
    float* __restrict__ y) {                 // [64][512][1024]
    __shared__ unsigned short wlds[32 * 2048];   // 128 KiB, swizzled
    __shared__ float sh[32][32];                 // gate tile
    __shared__ float sbias[32];

    const int tid  = threadIdx.x;
    const int wave = tid >> 6;
    const int lane = tid & 63;
    const int wg   = blockIdx.x;
    const int g    = wg >> 1;
    const int bgrp = wg & 1;

    // ---- prologue: stage weights + bias into LDS ----
    for (int ch = tid; ch < 8192; ch += 512) {
        int lr = ch >> 8;                 // local row 0..31
        int bo = (ch & 255) << 4;         // byte offset in row
        int q = lr >> 3, r = lr & 7;
        const unsigned short* src = wc + ((size_t)(q * HID + g * 8 + r) << 11) + (bo >> 1);
        short8 v = *(const short8*)src;
        *(short8*)((char*)wlds + lr * 4096 + (bo ^ ((lr & 7) << 4))) = v;
    }
    if (tid < 32) {
        int q = tid >> 3, r = tid & 7;
        sbias[tid] = bias[q * HID + g * 8 + r];
    }
    __syncthreads();

    const int mt    = wave & 1;
    const int nt    = (wave >> 1) & 1;
    const int kpart = wave >> 2;
    const int arow  = lane & 15;
    const int kgrp  = lane >> 4;

    const int n_glob = bgrp * 32 + mt * 16 + arow;   // batch row for A
    const size_t a_off = ((size_t)n_glob << 10) + kgrp * 8;
    const int brow = nt * 16 + arow;                  // LDS weight row (gate col)
    const unsigned int bsw = (unsigned int)(brow & 7) << 4;
    const char* bbase = (const char*)wlds + brow * 4096 + kpart * 2048;

    cg::grid_group grid = cg::this_grid();

    for (int t = 0; t < T_STEPS; ++t) {
        const unsigned short* hin = (t & 1) ? h1 : h0;
        unsigned short* hout      = (t & 1) ? h0 : h1;
        const unsigned short* aptr = kpart ? (hin + a_off)
                                           : (xb + ((size_t)t << 16) + a_off);
        f32x4 acc = {0.f, 0.f, 0.f, 0.f};
        #pragma unroll 8
        for (int kb = 0; kb < 32; ++kb) {
            short8 av = *(const short8*)(aptr + kb * 32);
            short8 bv = *(const short8*)(bbase + ((unsigned int)(kb * 64 + kgrp * 16) ^ bsw));
            acc = __builtin_amdgcn_mfma_f32_16x16x32_bf16(av, bv, acc, 0, 0, 0);
        }
        // C/D layout: col = lane&15, row = (lane>>4)*4 + r
        if (kpart == 0) {
            #pragma unroll
            for (int r = 0; r < 4; ++r)
                sh[mt * 16 + kgrp * 4 + r][nt * 16 + arow] = acc[r];
        }
        __syncthreads();
        if (kpart == 1) {
            #pragma unroll
            for (int r = 0; r < 4; ++r)
                sh[mt * 16 + kgrp * 4 + r][nt * 16 + arow] += acc[r];
        }
        __syncthreads();

        if (tid < 256) {
            int n = tid >> 3, j = tid & 7;
            float iv = sh[n][j]      + sbias[j];
            float fv = sh[n][8 + j]  + sbias[8 + j];
            float gv = sh[n][16 + j] + sbias[16 + j];
            float ov = sh[n][24 + j] + sbias[24 + j];
            iv = 1.f / (1.f + __expf(-iv));
            fv = 1.f / (1.f + __expf(-fv));
            ov = 1.f / (1.f + __expf(-ov));
            float eg = __expf(2.f * gv);
            gv = 1.f - 2.f / (eg + 1.f);
            int ng = bgrp * 32 + n, jg = g * 8 + j;
            size_t ci = ((size_t)ng << 10) + jg;
            float cc = fv * c[ci] + iv * gv;
            c[ci] = cc;
            float ec = __expf(2.f * cc);
            float th = 1.f - 2.f / (ec + 1.f);
            float hh = ov * th;
            y[((size_t)ng << 19) + ((size_t)t << 10) + jg] = hh;
            hout[ci] = f2bf(hh);
        }
        grid.sync();
    }
}

extern "C" void kernel_launch(void* const* d_in, const int* in_sizes, int n_in,
                              void* d_out, int out_size, void* d_ws, size_t ws_size,
                              hipStream_t stream) {
    const float* x   = (const float*)d_in[0];
    const float* wih = (const float*)d_in[1];
    const float* whh = (const float*)d_in[2];
    const float* bih = (const float*)d_in[3];
    const float* bhh = (const float*)d_in[4];
    float* y = (float*)d_out;

    char* ws = (char*)d_ws;
    unsigned short* Wc = (unsigned short*)ws;
    unsigned short* xb = (unsigned short*)(ws + ((size_t)16 << 20));
    float* bias        = (float*)(ws + ((size_t)80 << 20));
    float* c           = (float*)(ws + ((size_t)80 << 20) + (1u << 16));
    unsigned short* h0 = (unsigned short*)(ws + ((size_t)80 << 20) + (1u << 16) + (1u << 18));
    unsigned short* h1 = h0 + NB * HID;
    if (ws_size < ((size_t)81 << 20)) return;

    hipLaunchKernelGGL(cvt_w_kernel, dim3(4096), dim3(256), 0, stream, wih, whh, Wc);
    hipLaunchKernelGGL(cvt_x_kernel, dim3(16384), dim3(256), 0, stream, x, xb);
    hipLaunchKernelGGL(init_kernel, dim3(256), dim3(256), 0, stream, h0, c, bih, bhh, bias);

    void* args[] = {(void*)&xb, (void*)&Wc, (void*)&bias, (void*)&c,
                    (void*)&h0, (void*)&h1, (void*)&y};
    hipLaunchCooperativeKernel((const void*)lstm_persist, dim3(256), dim3(512),
                               args, 0, stream);
}

// Round 4
// 4894.453 us; speedup vs baseline: 4.1956x; 4.1956x over previous
//
#include <hip/hip_runtime.h>

#define T_STEPS 512
#define NB 64
#define D_IN 1024
#define HID 1024
#define G4 4096
#define KTOT 2048
#define NWG 256

typedef short short8 __attribute__((ext_vector_type(8)));
typedef float f32x4 __attribute__((ext_vector_type(4)));

static __device__ __forceinline__ unsigned short f2bf(float f) {
    unsigned int u = __builtin_bit_cast(unsigned int, f);
    u += 0x7fffu + ((u >> 16) & 1u);
    return (unsigned short)(u >> 16);
}

// Build Wc bf16 [4096][2048]: cols 0..1023 = W_ih row, 1024..2047 = W_hh row.
__global__ void cvt_w_kernel(const float* __restrict__ wih, const float* __restrict__ whh,
                             unsigned short* __restrict__ wc) {
    size_t idx = ((size_t)blockIdx.x * blockDim.x + threadIdx.x) * 8;
    if (idx >= (size_t)G4 * KTOT) return;
    int k = (int)(idx & (KTOT - 1));
    int g = (int)(idx >> 11);
    const float* src = (k < D_IN) ? (wih + (size_t)g * D_IN + k)
                                  : (whh + (size_t)g * HID + (k - D_IN));
    float4 a = *(const float4*)src;
    float4 b = *(const float4*)(src + 4);
    short8 v;
    v[0] = (short)f2bf(a.x); v[1] = (short)f2bf(a.y);
    v[2] = (short)f2bf(a.z); v[3] = (short)f2bf(a.w);
    v[4] = (short)f2bf(b.x); v[5] = (short)f2bf(b.y);
    v[6] = (short)f2bf(b.z); v[7] = (short)f2bf(b.w);
    *(short8*)(wc + idx) = v;
}

// x (N,T,D) fp32 -> xb (T,N,D) bf16
__global__ void cvt_x_kernel(const float* __restrict__ x, unsigned short* __restrict__ xb) {
    size_t idx = ((size_t)blockIdx.x * blockDim.x + threadIdx.x) * 8;
    if (idx >= (size_t)NB * T_STEPS * D_IN) return;
    int d = (int)(idx & (D_IN - 1));
    size_t nt = idx >> 10;           // n*512 + t
    int t = (int)(nt & (T_STEPS - 1));
    int n = (int)(nt >> 9);
    float4 a = *(const float4*)(x + idx);
    float4 b = *(const float4*)(x + idx + 4);
    short8 v;
    v[0] = (short)f2bf(a.x); v[1] = (short)f2bf(a.y);
    v[2] = (short)f2bf(a.z); v[3] = (short)f2bf(a.w);
    v[4] = (short)f2bf(b.x); v[5] = (short)f2bf(b.y);
    v[6] = (short)f2bf(b.z); v[7] = (short)f2bf(b.w);
    *(short8*)(xb + (((size_t)t * NB + n) << 10) + d) = v;
}

// Zero h0 and barrier counters (plain stores; flushed to memory at kernel end,
// visible to the persistent kernel's sc0sc1 bypass reads).
__global__ void init_kernel(unsigned int* __restrict__ h0w, unsigned int* __restrict__ cnt) {
    int i = blockIdx.x * blockDim.x + threadIdx.x;
    if (i < NB * HID / 2) h0w[i] = 0u;
    if (i < 1024) cnt[i] = 0u;
}

// Persistent LSTM: 256 WGs x 512 threads, 1 WG/CU.
// WG wg: g = wg>>1 owns hidden [g*8,+8) (32 gate rows); bgrp = wg&1 owns batch [bgrp*32,+32).
// Waves: mt = wave&1 (16-row half of batch tile), kq = wave>>1 (K slice of 512).
// kq 0,1 -> x part (plain cached loads); kq 2,3 -> h part (sc0 sc1 bypass loads from IF$).
// Weights LDS-resident, XOR-swizzled byte ^= (row&15)<<4.
// Cross-step sync: per-step arrive counter (device-scope atomicAdd) + tid0 spin on an
// sc0 sc1 load; h travels through IF$ via explicit sc0 sc1 stores/loads; c in registers.
// No cache-wide maintenance anywhere.
__global__ __launch_bounds__(512, 1) void lstm_persist(
    const unsigned short* __restrict__ xb,   // [512][64][1024] bf16
    const unsigned short* __restrict__ wc,   // [4096][2048] bf16
    const float* __restrict__ bih,
    const float* __restrict__ bhh,
    unsigned short* __restrict__ h0,         // [64][1024] bf16
    unsigned short* __restrict__ h1,
    unsigned int* __restrict__ cnt,          // [1024]
    float* __restrict__ y) {                 // [64][512][1024]
    __shared__ unsigned short wlds[32 * 2048];   // 128 KiB, swizzled
    __shared__ float shx[32][32];                // x-part partial
    __shared__ float shh[32][32];                // h-part partial
    __shared__ float sbias[32];

    const int tid  = threadIdx.x;
    const int wave = tid >> 6;
    const int lane = tid & 63;
    const int wg   = blockIdx.x;
    const int g    = wg >> 1;
    const int bgrp = wg & 1;

    // ---- prologue: stage weights + bias into LDS ----
    for (int ch = tid; ch < 8192; ch += 512) {
        int lr = ch >> 8;                 // local row 0..31
        unsigned int bo = (unsigned)((ch & 255) << 4);
        int q = lr >> 3, r = lr & 7;
        const unsigned short* src = wc + ((size_t)(q * HID + g * 8 + r) << 11) + (bo >> 1);
        short8 v = *(const short8*)src;
        *(short8*)((char*)wlds + lr * 4096 + (bo ^ (((unsigned)lr & 15u) << 4))) = v;
    }
    if (tid < 32) {
        int q = tid >> 3, r = tid & 7;
        int gr = q * HID + g * 8 + r;
        sbias[tid] = bih[gr] + bhh[gr];
    }
    __syncthreads();

    const int mt   = wave & 1;
    const int kq   = wave >> 1;        // 0..3, K slice [kq*512, +512)
    const int arow = lane & 15;
    const int kgrp = lane >> 4;

    const int n_glob = bgrp * 32 + mt * 16 + arow;
    const unsigned int bswz = ((unsigned)arow & 15u) << 4;   // (16+arow)&15 == arow
    const unsigned int bcol = (unsigned)(kq * 1024 + kgrp * 16);
    const char* wbase = (const char*)wlds;

    // register-resident cell state: pointwise thread (tid<128) owns (n, j0=2*(tid&3)) pair
    float creg0 = 0.f, creg1 = 0.f;

    for (int t = 0; t < T_STEPS; ++t) {
        const unsigned short* hin = (t & 1) ? h1 : h0;
        unsigned short* hout      = (t & 1) ? h0 : h1;

        // ---- A-fragment preload (16 frags = K 512) ----
        short8 afrag[16];
        if (kq < 2) {
            const unsigned short* ap = xb + ((size_t)t << 16) + ((size_t)n_glob << 10)
                                          + kq * 512 + kgrp * 8;
            #pragma unroll
            for (int kb = 0; kb < 16; ++kb) afrag[kb] = *(const short8*)(ap + kb * 32);
        } else {
            const unsigned short* ap = hin + ((size_t)n_glob << 10) + (kq - 2) * 512 + kgrp * 8;
            #pragma unroll
            for (int kb = 0; kb < 16; ++kb) {
                asm volatile("global_load_dwordx4 %0, %1, off sc0 sc1"
                             : "=v"(afrag[kb]) : "v"(ap + kb * 32) : "memory");
            }
            asm volatile("s_waitcnt vmcnt(0)" ::: "memory");
            __builtin_amdgcn_sched_barrier(0);
        }

        // ---- MFMA: 16 rows x 32 gate-cols, K=512 per wave ----
        f32x4 acc0 = {0.f,0.f,0.f,0.f}, acc1 = {0.f,0.f,0.f,0.f};
        #pragma unroll
        for (int kb = 0; kb < 16; ++kb) {
            unsigned int co = bcol + (unsigned)(kb * 64);
            short8 b0 = *(const short8*)(wbase + arow * 4096        + (co ^ bswz));
            short8 b1 = *(const short8*)(wbase + (16 + arow) * 4096 + (co ^ bswz));
            acc0 = __builtin_amdgcn_mfma_f32_16x16x32_bf16(afrag[kb], b0, acc0, 0, 0, 0);
            acc1 = __builtin_amdgcn_mfma_f32_16x16x32_bf16(afrag[kb], b1, acc1, 0, 0, 0);
        }

        // ---- reduce K-slices via LDS: phase A write (kq 0,2), phase B add (kq 1,3) ----
        // C/D layout: col = lane&15, row = kgrp*4 + r
        if (kq == 0) {
            #pragma unroll
            for (int r = 0; r < 4; ++r) {
                shx[mt * 16 + kgrp * 4 + r][arow]      = acc0[r];
                shx[mt * 16 + kgrp * 4 + r][16 + arow] = acc1[r];
            }
        } else if (kq == 2) {
            #pragma unroll
            for (int r = 0; r < 4; ++r) {
                shh[mt * 16 + kgrp * 4 + r][arow]      = acc0[r];
                shh[mt * 16 + kgrp * 4 + r][16 + arow] = acc1[r];
            }
        }
        __syncthreads();
        if (kq == 1) {
            #pragma unroll
            for (int r = 0; r < 4; ++r) {
                shx[mt * 16 + kgrp * 4 + r][arow]      += acc0[r];
                shx[mt * 16 + kgrp * 4 + r][16 + arow] += acc1[r];
            }
        } else if (kq == 3) {
            #pragma unroll
            for (int r = 0; r < 4; ++r) {
                shh[mt * 16 + kgrp * 4 + r][arow]      += acc0[r];
                shh[mt * 16 + kgrp * 4 + r][16 + arow] += acc1[r];
            }
        }
        __syncthreads();

        // ---- pointwise: 128 threads, 2 adjacent hidden units each ----
        if (tid < 128) {
            int n  = tid >> 2;
            int j0 = (tid & 3) * 2;
            float hv[2];
            float cc[2] = {creg0, creg1};
            #pragma unroll
            for (int e = 0; e < 2; ++e) {
                int j = j0 + e;
                float iv = shx[n][j]      + shh[n][j]      + sbias[j];
                float fv = shx[n][8 + j]  + shh[n][8 + j]  + sbias[8 + j];
                float gv = shx[n][16 + j] + shh[n][16 + j] + sbias[16 + j];
                float ov = shx[n][24 + j] + shh[n][24 + j] + sbias[24 + j];
                iv = 1.f / (1.f + __expf(-iv));
                fv = 1.f / (1.f + __expf(-fv));
                ov = 1.f / (1.f + __expf(-ov));
                float eg = __expf(2.f * gv);
                gv = 1.f - 2.f / (eg + 1.f);
                float c2 = fv * cc[e] + iv * gv;
                cc[e] = c2;
                float ec = __expf(2.f * c2);
                hv[e] = ov * (1.f - 2.f / (ec + 1.f));
            }
            creg0 = cc[0]; creg1 = cc[1];
            int ng = bgrp * 32 + n, jg0 = g * 8 + j0;
            *(float2*)(y + ((size_t)ng << 19) + ((size_t)t << 10) + jg0)
                = make_float2(hv[0], hv[1]);
            unsigned int hpack = (unsigned)f2bf(hv[0]) | ((unsigned)f2bf(hv[1]) << 16);
            unsigned int* hw = (unsigned int*)hout + ((((size_t)ng << 10) + jg0) >> 1);
            asm volatile("global_store_dword %0, %1, off sc0 sc1"
                         :: "v"(hw), "v"(hpack) : "memory");
        }

        // ---- lightweight global barrier (no cache maintenance) ----
        if (t != T_STEPS - 1) {
            asm volatile("s_waitcnt vmcnt(0)" ::: "memory");  // h stores at IF$
            __syncthreads();
            if (tid == 0) {
                atomicAdd(cnt + t, 1u);   // device-scope (G12/m20)
                unsigned int cv = 0;
                int guard = 0;
                do {
                    asm volatile("global_load_dword %0, %1, off sc0 sc1\n\t"
                                 "s_waitcnt vmcnt(0)"
                                 : "=v"(cv) : "v"(cnt + t) : "memory");
                } while (cv < NWG && ++guard < 5000000);
            }
            __syncthreads();
        }
    }
}

extern "C" void kernel_launch(void* const* d_in, const int* in_sizes, int n_in,
                              void* d_out, int out_size, void* d_ws, size_t ws_size,
                              hipStream_t stream) {
    const float* x   = (const float*)d_in[0];
    const float* wih = (const float*)d_in[1];
    const float* whh = (const float*)d_in[2];
    const float* bih = (const float*)d_in[3];
    const float* bhh = (const float*)d_in[4];
    float* y = (float*)d_out;

    char* ws = (char*)d_ws;
    unsigned short* Wc = (unsigned short*)ws;                         // 16 MiB
    unsigned short* xb = (unsigned short*)(ws + ((size_t)16 << 20));  // 64 MiB
    unsigned short* h0 = (unsigned short*)(ws + ((size_t)80 << 20));            // 128 KiB
    unsigned short* h1 = (unsigned short*)(ws + ((size_t)80 << 20) + (1u<<17)); // 128 KiB
    unsigned int* cnt  = (unsigned int*)(ws + ((size_t)80 << 20) + (1u<<18));   // 4 KiB
    if (ws_size < ((size_t)81 << 20)) return;

    hipLaunchKernelGGL(cvt_w_kernel, dim3(4096), dim3(256), 0, stream, wih, whh, Wc);
    hipLaunchKernelGGL(cvt_x_kernel, dim3(16384), dim3(256), 0, stream, x, xb);
    hipLaunchKernelGGL(init_kernel, dim3(256), dim3(256), 0, stream,
                       (unsigned int*)h0, cnt);

    void* args[] = {(void*)&xb, (void*)&Wc, (void*)&bih, (void*)&bhh,
                    (void*)&h0, (void*)&h1, (void*)&cnt, (void*)&y};
    hipLaunchCooperativeKernel((const void*)lstm_persist, dim3(NWG), dim3(512),
                               args, 0, stream);
}

// Round 5
// 4295.575 us; speedup vs baseline: 4.7805x; 1.1394x over previous
//
#include <hip/hip_runtime.h>

#define T_STEPS 512
#define NB 64
#define D_IN 1024
#define HID 1024
#define G4 4096
#define KTOT 2048
#define NWG 256

typedef short short8 __attribute__((ext_vector_type(8)));
typedef float f32x4 __attribute__((ext_vector_type(4)));
typedef unsigned int u32x4 __attribute__((ext_vector_type(4)));

static __device__ __forceinline__ unsigned short f2bf(float f) {
    unsigned int u = __builtin_bit_cast(unsigned int, f);
    u += 0x7fffu + ((u >> 16) & 1u);
    return (unsigned short)(u >> 16);
}

// Build Wc bf16 [4096][2048]: cols 0..1023 = W_ih row, 1024..2047 = W_hh row.
__global__ void cvt_w_kernel(const float* __restrict__ wih, const float* __restrict__ whh,
                             unsigned short* __restrict__ wc) {
    size_t idx = ((size_t)blockIdx.x * blockDim.x + threadIdx.x) * 8;
    if (idx >= (size_t)G4 * KTOT) return;
    int k = (int)(idx & (KTOT - 1));
    int g = (int)(idx >> 11);
    const float* src = (k < D_IN) ? (wih + (size_t)g * D_IN + k)
                                  : (whh + (size_t)g * HID + (k - D_IN));
    float4 a = *(const float4*)src;
    float4 b = *(const float4*)(src + 4);
    short8 v;
    v[0] = (short)f2bf(a.x); v[1] = (short)f2bf(a.y);
    v[2] = (short)f2bf(a.z); v[3] = (short)f2bf(a.w);
    v[4] = (short)f2bf(b.x); v[5] = (short)f2bf(b.y);
    v[6] = (short)f2bf(b.z); v[7] = (short)f2bf(b.w);
    *(short8*)(wc + idx) = v;
}

// x (N,T,D) fp32 -> xb (T,N,D) bf16
__global__ void cvt_x_kernel(const float* __restrict__ x, unsigned short* __restrict__ xb) {
    size_t idx = ((size_t)blockIdx.x * blockDim.x + threadIdx.x) * 8;
    if (idx >= (size_t)NB * T_STEPS * D_IN) return;
    int d = (int)(idx & (D_IN - 1));
    size_t nt = idx >> 10;           // n*512 + t
    int t = (int)(nt & (T_STEPS - 1));
    int n = (int)(nt >> 9);
    float4 a = *(const float4*)(x + idx);
    float4 b = *(const float4*)(x + idx + 4);
    short8 v;
    v[0] = (short)f2bf(a.x); v[1] = (short)f2bf(a.y);
    v[2] = (short)f2bf(a.z); v[3] = (short)f2bf(a.w);
    v[4] = (short)f2bf(b.x); v[5] = (short)f2bf(b.y);
    v[6] = (short)f2bf(b.z); v[7] = (short)f2bf(b.w);
    *(short8*)(xb + (((size_t)t * NB + n) << 10) + d) = v;
}

// Zero h0 and flags (plain stores; kernel-end implicit device release makes them
// visible to the persistent kernel's sc0sc1 bypass reads -- proven in round 4).
__global__ void init_kernel(unsigned int* __restrict__ h0w, unsigned int* __restrict__ flg) {
    int i = blockIdx.x * blockDim.x + threadIdx.x;
    if (i < NB * HID / 2) h0w[i] = 0u;
    if (i < 1024) flg[i] = 0u;
}

// Persistent LSTM: 256 WGs x 512 threads, 1 WG/CU.
// WG wg: g = wg>>1 owns hidden [g*8,+8) (32 gate rows); bgrp = wg&1 owns batch [bgrp*32,+32).
// Waves 0-3 = x-team (mt = wave&1, kh = (wave>>1)&1): at iter t compute the x-projection
//   for step t+1 into sx[(t+1)&1] -- fully overlapped with the barrier/h phase.
//   Waves 0-3 also run the pointwise (tid<256), then set their per-wave arrive flag.
// Waves 4-7 = h-team: poll all 256 WGs' flag quads (1 WG per lane, pure sc0sc1 loads,
//   no atomics), bypass-load h(t), MFMA, write shh. One __syncthreads per step.
// Safety: h-team passing poll(t) implies its OWN pointwise(t-1) finished (own flags == t),
//   so shh overwrite and sx buffer reuse are ordered without extra barriers.
__global__ __launch_bounds__(512, 1) void lstm_persist(
    const unsigned short* __restrict__ xb,   // [512][64][1024] bf16
    const unsigned short* __restrict__ wc,   // [4096][2048] bf16
    const float* __restrict__ bih,
    const float* __restrict__ bhh,
    unsigned short* __restrict__ h0,         // [64][1024] bf16 (step-even input)
    unsigned short* __restrict__ h1,
    unsigned int* __restrict__ flags,        // [256][4] per-WG per-wave arrive flags
    float* __restrict__ y) {                 // [64][512][1024]
    __shared__ unsigned short wlds[32 * 2048];   // 128 KiB, swizzled
    __shared__ float sx[2][2][32][36];           // [buf][khalf][row][col] x-part
    __shared__ float shh[2][32][36];             // [khalf][row][col]     h-part
    __shared__ float sbias[32];

    const int tid  = threadIdx.x;
    const int wave = tid >> 6;
    const int lane = tid & 63;
    const int wg   = blockIdx.x;
    const int g    = wg >> 1;
    const int bgrp = wg & 1;

    // ---- prologue: stage weights + bias into LDS ----
    for (int ch = tid; ch < 8192; ch += 512) {
        int lr = ch >> 8;
        unsigned int bo = (unsigned)((ch & 255) << 4);
        int q = lr >> 3, r = lr & 7;
        const unsigned short* src = wc + ((size_t)(q * HID + g * 8 + r) << 11) + (bo >> 1);
        short8 v = *(const short8*)src;
        *(short8*)((char*)wlds + lr * 4096 + (bo ^ (((unsigned)lr & 15u) << 4))) = v;
    }
    if (tid < 32) {
        int q = tid >> 3, r = tid & 7;
        int gr = q * HID + g * 8 + r;
        sbias[tid] = bih[gr] + bhh[gr];
    }
    __syncthreads();

    const int team = wave >> 2;          // 0 = x-team, 1 = h-team
    const int mt   = wave & 1;
    const int kh   = (wave >> 1) & 1;    // K half within the 1024 of this part
    const int arow = lane & 15;
    const int kgrp = lane >> 4;
    const int n_glob = bgrp * 32 + mt * 16 + arow;
    const unsigned int bswz = ((unsigned)arow & 15u) << 4;
    const char* wbase = (const char*)wlds;
    const int wgp = ((wave - 4) << 6) | lane;   // h-team: WG whose flags this lane polls

    float creg = 0.f;   // cell state (pointwise threads, tid<256)

    // ---- prologue: x-projection for step 0 into sx[0] ----
    if (team == 0) {
        const unsigned short* ap = xb + ((size_t)n_glob << 10) + kh * 512 + kgrp * 8;
        short8 af[16];
        #pragma unroll
        for (int kb = 0; kb < 16; ++kb) af[kb] = *(const short8*)(ap + kb * 32);
        f32x4 a0 = {0.f,0.f,0.f,0.f}, a1 = {0.f,0.f,0.f,0.f};
        #pragma unroll
        for (int kb = 0; kb < 16; ++kb) {
            unsigned o = (unsigned)(kh * 1024 + kgrp * 16 + kb * 64);
            short8 b0 = *(const short8*)(wbase + arow * 4096        + (o ^ bswz));
            short8 b1 = *(const short8*)(wbase + (16 + arow) * 4096 + (o ^ bswz));
            a0 = __builtin_amdgcn_mfma_f32_16x16x32_bf16(af[kb], b0, a0, 0, 0, 0);
            a1 = __builtin_amdgcn_mfma_f32_16x16x32_bf16(af[kb], b1, a1, 0, 0, 0);
        }
        #pragma unroll
        for (int r = 0; r < 4; ++r) {
            sx[0][kh][mt * 16 + kgrp * 4 + r][arow]      = a0[r];
            sx[0][kh][mt * 16 + kgrp * 4 + r][16 + arow] = a1[r];
        }
    }

    for (int t = 0; t < T_STEPS; ++t) {
        const int cb = t & 1;
        if (team == 0) {
            // ---- x-projection for step t+1 into sx[cb^1] (no barrier dependence) ----
            int s = (t + 1 < T_STEPS) ? t + 1 : T_STEPS - 1;
            const unsigned short* ap = xb + ((size_t)s << 16) + ((size_t)n_glob << 10)
                                          + kh * 512 + kgrp * 8;
            short8 af[16];
            #pragma unroll
            for (int kb = 0; kb < 16; ++kb) af[kb] = *(const short8*)(ap + kb * 32);
            f32x4 a0 = {0.f,0.f,0.f,0.f}, a1 = {0.f,0.f,0.f,0.f};
            #pragma unroll
            for (int kb = 0; kb < 16; ++kb) {
                unsigned o = (unsigned)(kh * 1024 + kgrp * 16 + kb * 64);
                short8 b0 = *(const short8*)(wbase + arow * 4096        + (o ^ bswz));
                short8 b1 = *(const short8*)(wbase + (16 + arow) * 4096 + (o ^ bswz));
                a0 = __builtin_amdgcn_mfma_f32_16x16x32_bf16(af[kb], b0, a0, 0, 0, 0);
                a1 = __builtin_amdgcn_mfma_f32_16x16x32_bf16(af[kb], b1, a1, 0, 0, 0);
            }
            #pragma unroll
            for (int r = 0; r < 4; ++r) {
                sx[cb ^ 1][kh][mt * 16 + kgrp * 4 + r][arow]      = a0[r];
                sx[cb ^ 1][kh][mt * 16 + kgrp * 4 + r][16 + arow] = a1[r];
            }
        } else {
            // ---- wait for h(t): poll this lane's WG flag quad (pure loads) ----
            if (t > 0) {
                const u32x4* fp = (const u32x4*)flags + wgp;
                unsigned tgt = (unsigned)t;
                int guard = 0;
                while (true) {
                    u32x4 f;
                    asm volatile("global_load_dwordx4 %0, %1, off sc0 sc1\n\t"
                                 "s_waitcnt vmcnt(0)"
                                 : "=v"(f) : "v"(fp) : "memory");
                    int ok = (f[0] >= tgt) & (f[1] >= tgt) & (f[2] >= tgt) & (f[3] >= tgt);
                    if (__all(ok) || ++guard > 3000000) break;
                }
            }
            // ---- bypass-load h(t), MFMA, write shh ----
            const unsigned short* hin = cb ? h1 : h0;
            const unsigned short* ap = hin + ((size_t)n_glob << 10) + kh * 512 + kgrp * 8;
            short8 af[16];
            #pragma unroll
            for (int kb = 0; kb < 16; ++kb)
                asm volatile("global_load_dwordx4 %0, %1, off sc0 sc1"
                             : "=v"(af[kb]) : "v"(ap + kb * 32) : "memory");
            asm volatile("s_waitcnt vmcnt(0)" ::: "memory");
            __builtin_amdgcn_sched_barrier(0);
            f32x4 a0 = {0.f,0.f,0.f,0.f}, a1 = {0.f,0.f,0.f,0.f};
            #pragma unroll
            for (int kb = 0; kb < 16; ++kb) {
                unsigned o = (unsigned)(2048 + kh * 1024 + kgrp * 16 + kb * 64);
                short8 b0 = *(const short8*)(wbase + arow * 4096        + (o ^ bswz));
                short8 b1 = *(const short8*)(wbase + (16 + arow) * 4096 + (o ^ bswz));
                a0 = __builtin_amdgcn_mfma_f32_16x16x32_bf16(af[kb], b0, a0, 0, 0, 0);
                a1 = __builtin_amdgcn_mfma_f32_16x16x32_bf16(af[kb], b1, a1, 0, 0, 0);
            }
            #pragma unroll
            for (int r = 0; r < 4; ++r) {
                shh[kh][mt * 16 + kgrp * 4 + r][arow]      = a0[r];
                shh[kh][mt * 16 + kgrp * 4 + r][16 + arow] = a1[r];
            }
        }
        __syncthreads();   // publish sx[cb^1] (for t+1) and shh (for t)

        // ---- pointwise on x-team (tid<256): 1 hidden unit each ----
        if (tid < 256) {
            int n = tid >> 3, j = tid & 7;
            float iv = sx[cb][0][n][j]      + sx[cb][1][n][j]      + shh[0][n][j]      + shh[1][n][j]      + sbias[j];
            float fv = sx[cb][0][n][8 + j]  + sx[cb][1][n][8 + j]  + shh[0][n][8 + j]  + shh[1][n][8 + j]  + sbias[8 + j];
            float gv = sx[cb][0][n][16 + j] + sx[cb][1][n][16 + j] + shh[0][n][16 + j] + shh[1][n][16 + j] + sbias[16 + j];
            float ov = sx[cb][0][n][24 + j] + sx[cb][1][n][24 + j] + shh[0][n][24 + j] + shh[1][n][24 + j] + sbias[24 + j];
            iv = 1.f / (1.f + __expf(-iv));
            fv = 1.f / (1.f + __expf(-fv));
            ov = 1.f / (1.f + __expf(-ov));
            float eg = __expf(2.f * gv);
            gv = 1.f - 2.f / (eg + 1.f);
            float c2 = fv * creg + iv * gv;
            creg = c2;
            float ec = __expf(2.f * c2);
            float hh = ov * (1.f - 2.f / (ec + 1.f));
            int ng = bgrp * 32 + n, jg = g * 8 + j;
            y[((size_t)ng << 19) + ((size_t)t << 10) + jg] = hh;
            unsigned short* hw = (cb ? h0 : h1) + ((size_t)ng << 10) + jg;
            unsigned int hp = (unsigned int)f2bf(hh);
            asm volatile("global_store_short %0, %1, off sc0 sc1"
                         :: "v"(hw), "v"(hp) : "memory");
            // drain this wave's h stores, then arrive (per-wave flag dword)
            asm volatile("s_waitcnt vmcnt(0)" ::: "memory");
            if ((tid & 63) == 0) {
                unsigned int* fw = flags + (wg << 2) + (tid >> 6);
                unsigned int tv = (unsigned int)(t + 1);
                asm volatile("global_store_dword %0, %1, off sc0 sc1"
                             :: "v"(fw), "v"(tv) : "memory");
            }
        }
    }
}

extern "C" void kernel_launch(void* const* d_in, const int* in_sizes, int n_in,
                              void* d_out, int out_size, void* d_ws, size_t ws_size,
                              hipStream_t stream) {
    const float* x   = (const float*)d_in[0];
    const float* wih = (const float*)d_in[1];
    const float* whh = (const float*)d_in[2];
    const float* bih = (const float*)d_in[3];
    const float* bhh = (const float*)d_in[4];
    float* y = (float*)d_out;

    char* ws = (char*)d_ws;
    unsigned short* Wc = (unsigned short*)ws;                         // 16 MiB
    unsigned short* xb = (unsigned short*)(ws + ((size_t)16 << 20));  // 64 MiB
    unsigned short* h0 = (unsigned short*)(ws + ((size_t)80 << 20));            // 128 KiB
    unsigned short* h1 = (unsigned short*)(ws + ((size_t)80 << 20) + (1u<<17)); // 128 KiB
    unsigned int* flg  = (unsigned int*)(ws + ((size_t)80 << 20) + (1u<<18));   // 4 KiB
    if (ws_size < ((size_t)81 << 20)) return;

    hipLaunchKernelGGL(cvt_w_kernel, dim3(4096), dim3(256), 0, stream, wih, whh, Wc);
    hipLaunchKernelGGL(cvt_x_kernel, dim3(16384), dim3(256), 0, stream, x, xb);
    hipLaunchKernelGGL(init_kernel, dim3(256), dim3(256), 0, stream,
                       (unsigned int*)h0, flg);

    void* args[] = {(void*)&xb, (void*)&Wc, (void*)&bih, (void*)&bhh,
                    (void*)&h0, (void*)&h1, (void*)&flg, (void*)&y};
    hipLaunchCooperativeKernel((const void*)lstm_persist, dim3(NWG), dim3(512),
                               args, 0, stream);
}

// Round 8
// 3272.963 us; speedup vs baseline: 6.2742x; 1.3124x over previous
//
#include <hip/hip_runtime.h>

#define HID 1024
#define G4 4096
#define TCH 128
#define NCH 4
#define NWG 256

typedef short short8 __attribute__((ext_vector_type(8)));
typedef float f32x4 __attribute__((ext_vector_type(4)));
typedef unsigned int u32x4 __attribute__((ext_vector_type(4)));

static __device__ __forceinline__ unsigned short f2bf(float f) {
    unsigned int u = __builtin_bit_cast(unsigned int, f);
    u += 0x7fffu + ((u >> 16) & 1u);
    return (unsigned short)(u >> 16);
}
static __device__ __forceinline__ float bf2f(unsigned short u) {
    unsigned int x = ((unsigned int)u) << 16;
    return __builtin_bit_cast(float, x);
}
static __device__ __forceinline__ unsigned short f2h(float v) {
    _Float16 h = (_Float16)v;
    return __builtin_bit_cast(unsigned short, h);
}
static __device__ __forceinline__ float h2f(unsigned short u) {
    return (float)__builtin_bit_cast(_Float16, u);
}

// fp32 -> bf16 bulk convert (n8 groups of 8)
__global__ void cvt_mat(const float* __restrict__ src, unsigned short* __restrict__ dst, int n8) {
    int idx = blockIdx.x * blockDim.x + threadIdx.x;
    if (idx >= n8) return;
    const float* s = src + (size_t)idx * 8;
    float4 a = *(const float4*)s;
    float4 b = *(const float4*)(s + 4);
    short8 v;
    v[0]=(short)f2bf(a.x); v[1]=(short)f2bf(a.y); v[2]=(short)f2bf(a.z); v[3]=(short)f2bf(a.w);
    v[4]=(short)f2bf(b.x); v[5]=(short)f2bf(b.y); v[6]=(short)f2bf(b.z); v[7]=(short)f2bf(b.w);
    *(short8*)(dst + (size_t)idx * 8) = v;
}

// zero state region (hcan, cws, hx tags), combine biases, bump per-replay nonce
__global__ void init_kernel(const float* __restrict__ bih, const float* __restrict__ bhh,
                            float* __restrict__ biasc, unsigned int* __restrict__ zbase,
                            int nz, unsigned int* __restrict__ nonce) {
    int i = blockIdx.x * blockDim.x + threadIdx.x;
    if (i < nz) zbase[i] = 0u;
    if (i < G4) biasc[i] = bih[i] + bhh[i];
    if (i == 0) nonce[0] = nonce[0] + 1u;
}

// xg[m][g] = sum_k x_chunk[m][k]*Wih[g][k], m = tl*64 + n; output f16 bits.
__global__ __launch_bounds__(256) void xg_gemm(
    const float* __restrict__ x,            // [64][512][1024] fp32
    const unsigned short* __restrict__ wb,  // Wih_bf [4096][1024]
    unsigned short* __restrict__ xg,        // [TCH*64][4096] f16 chunk
    int t0) {
    __shared__ unsigned short Al[128][72];
    __shared__ unsigned short Bl[128][72];
    const int tid = threadIdx.x, w = tid >> 6, lane = tid & 63;
    const int bm = blockIdx.x >> 5, bn = blockIdx.x & 31;
    const int wr = w >> 1, wc = w & 1;
    const int fr = lane & 15, kg = lane >> 4;
    f32x4 acc[4][4];
    #pragma unroll
    for (int i = 0; i < 4; ++i)
        #pragma unroll
        for (int j = 0; j < 4; ++j) acc[i][j] = (f32x4){0.f,0.f,0.f,0.f};

    for (int kt = 0; kt < 16; ++kt) {
        __syncthreads();
        #pragma unroll
        for (int c = 0; c < 4; ++c) {
            int idx = c * 256 + tid;
            int row = idx >> 3, co = (idx & 7) * 8;
            int m = bm * 128 + row;
            const float* sp = x + ((size_t)(m & 63) * 512 + (size_t)(t0 + (m >> 6))) * 1024
                                + kt * 64 + co;
            float4 a = *(const float4*)sp;
            float4 b = *(const float4*)(sp + 4);
            short8 v;
            v[0]=(short)f2bf(a.x); v[1]=(short)f2bf(a.y); v[2]=(short)f2bf(a.z); v[3]=(short)f2bf(a.w);
            v[4]=(short)f2bf(b.x); v[5]=(short)f2bf(b.y); v[6]=(short)f2bf(b.z); v[7]=(short)f2bf(b.w);
            *(short8*)&Al[row][co] = v;
            *(short8*)&Bl[row][co] = *(const short8*)(wb + (size_t)(bn * 128 + row) * 1024 + kt * 64 + co);
        }
        __syncthreads();
        #pragma unroll
        for (int kb = 0; kb < 2; ++kb) {
            short8 af[4], bf_[4];
            #pragma unroll
            for (int mi = 0; mi < 4; ++mi)
                af[mi] = *(const short8*)&Al[wr*64 + mi*16 + fr][kb*32 + kg*8];
            #pragma unroll
            for (int ni = 0; ni < 4; ++ni)
                bf_[ni] = *(const short8*)&Bl[wc*64 + ni*16 + fr][kb*32 + kg*8];
            #pragma unroll
            for (int mi = 0; mi < 4; ++mi)
                #pragma unroll
                for (int ni = 0; ni < 4; ++ni)
                    acc[mi][ni] = __builtin_amdgcn_mfma_f32_16x16x32_bf16(af[mi], bf_[ni], acc[mi][ni], 0, 0, 0);
        }
    }
    #pragma unroll
    for (int mi = 0; mi < 4; ++mi)
        #pragma unroll
        for (int ni = 0; ni < 4; ++ni)
            #pragma unroll
            for (int r = 0; r < 4; ++r) {
                int row = bm*128 + wr*64 + mi*16 + kg*4 + r;
                int col = bn*128 + wc*64 + ni*16 + fr;
                xg[(size_t)row * 4096 + col] = f2h(acc[mi][ni][r]);
            }
}

// Persistent LSTM chunk (128 steps). 256 WGs x 512 thr.
// 8 INDEPENDENT groups: G = blockIdx>>5 owns batch rows [G*8,+8); member l = blockIdx&31
// owns hidden units [l*32,+32) (all 4 gate types -> pointwise WG-local). Whh slice
// (128 gate rows x K=1024) in 128 VGPRs/thread. NO cross-group sync of any kind.
// h exchange within group: u32 words {tag16 | h_bf16} via sc0 sc1 (device scope,
// round-4/5-proven). Producer: one fire-and-forget dword store per element (no drain,
// no flag, no barrier). Consumer: poll-loads ARE the data loads. Double buffer by
// step parity + per-step tags (nonce-salted per replay) -> no overwrite/staleness race.
__global__ __launch_bounds__(512, 2) void lstm_persist(
    const unsigned short* __restrict__ whh,   // Whh_bf [4096][1024]
    const unsigned short* __restrict__ xg,    // [TCH*64][4096] f16 bits
    const float* __restrict__ biasc,          // [4096]
    unsigned short* __restrict__ hcan,        // [64][1024] bf16 chunk-boundary h
    unsigned int* __restrict__ hx,            // [2][8][8][1024] u32 tagged h
    float* __restrict__ cws,                  // [64][1024] chunk-boundary c
    const unsigned int* __restrict__ nonce,   // [1]
    float* __restrict__ y, int t0) {
    __shared__ unsigned short hA[16 * 1024];   // [16][1024] bf16, rows 8..15 zero, swizzled
    __shared__ float sgate[4][2][8][16];
    __shared__ float sbias[4][32];

    const int tid = threadIdx.x, w = tid >> 6, lane = tid & 63;
    const int G = (int)(blockIdx.x >> 5);
    const int l = (int)(blockIdx.x & 31);

    for (int i = tid; i < 8192; i += 512) hA[8192 + i] = 0;   // zero pad rows 8..15
    if (tid < 128) {
        int q = tid >> 5, j = tid & 31;
        sbias[q][j] = biasc[q * 1024 + l * 32 + j];
    }
    const int q = w & 3, hu = w >> 2;
    const int col = lane & 15, kg = lane >> 4;
    const unsigned int nonce6 = nonce[0] & 63u;

    short8 bfr[32];   // Whh rows q*1024 + l*32 + hu*16 + col, K=1024
    {
        const unsigned short* wp = whh + (size_t)(q * 1024 + l * 32 + hu * 16 + col) * 1024 + kg * 8;
        #pragma unroll
        for (int kb = 0; kb < 32; ++kb) bfr[kb] = *(const short8*)(wp + kb * 32);
    }
    float creg = 0.f;
    if (tid < 256) {
        int n = tid >> 5, j = tid & 31;
        creg = cws[((size_t)(G * 8 + n) << 10) + l * 32 + j];
    }
    __syncthreads();

    const int sn = tid >> 6;   // staging batch row 0..7
    unsigned int* hxb0 = hx + (size_t)G * 8192;
    unsigned int* hxb1 = hx + (size_t)(8 + G) * 8192;

    for (int s = 0; s < TCH; ++s) {
        const int t = t0 + s;
        // ---- xg prefetch (L2 hit, hides under poll/stage) ----
        unsigned short xi = 0, xf = 0, xgv = 0, xo = 0;
        if (tid < 256) {
            int n = tid >> 5, j = tid & 31;
            const unsigned short* xp = xg + ((size_t)(s * 64 + G * 8 + n) << 12) + l * 32 + j;
            xi = xp[0]; xf = xp[1024]; xgv = xp[2048]; xo = xp[3072];
        }
        // ---- acquire h(t), stage into hA (XOR-swizzled 16B groups) ----
        short8 v0, v1;
        if (s == 0) {
            const unsigned short* hp = hcan + ((size_t)(G * 8 + sn) << 10) + lane * 16;
            v0 = *(const short8*)hp;
            v1 = *(const short8*)(hp + 8);
        } else {
            const unsigned int* pp = ((t & 1) ? hxb1 : hxb0) + sn * 1024 + lane * 16;
            const unsigned int ttag = (nonce6 << 10) | ((unsigned)t & 1023u);
            u32x4 w0, w1, w2, w3;
            int guard = 0;
            while (true) {
                asm volatile("global_load_dwordx4 %0, %1, off sc0 sc1" : "=v"(w0) : "v"(pp)      : "memory");
                asm volatile("global_load_dwordx4 %0, %1, off sc0 sc1" : "=v"(w1) : "v"(pp + 4)  : "memory");
                asm volatile("global_load_dwordx4 %0, %1, off sc0 sc1" : "=v"(w2) : "v"(pp + 8)  : "memory");
                asm volatile("global_load_dwordx4 %0, %1, off sc0 sc1" : "=v"(w3) : "v"(pp + 12) : "memory");
                asm volatile("s_waitcnt vmcnt(0)"
                             : "+v"(w0), "+v"(w1), "+v"(w2), "+v"(w3) :: "memory");
                int ok = 1;
                #pragma unroll
                for (int e = 0; e < 4; ++e) {
                    ok &= ((w0[e] >> 16) == ttag);
                    ok &= ((w1[e] >> 16) == ttag);
                    ok &= ((w2[e] >> 16) == ttag);
                    ok &= ((w3[e] >> 16) == ttag);
                }
                if (__all(ok) || ++guard > 100000) break;
            }
            #pragma unroll
            for (int e = 0; e < 4; ++e) {
                v0[e]     = (short)(w0[e] & 0xffffu);
                v0[4 + e] = (short)(w1[e] & 0xffffu);
                v1[e]     = (short)(w2[e] & 0xffffu);
                v1[4 + e] = (short)(w3[e] & 0xffffu);
            }
        }
        {
            int cg0 = lane * 2;
            char* base = (char*)hA + sn * 2048;
            *(short8*)(base + (((unsigned)(cg0       ^ (sn & 7))) << 4)) = v0;
            *(short8*)(base + (((unsigned)((cg0 + 1) ^ (sn & 7))) << 4)) = v1;
        }
        __syncthreads();
        // ---- recurrent MFMA: M=16 (8 real rows) x N=16 units x K=1024 ----
        f32x4 acc0 = {0.f,0.f,0.f,0.f}, acc1 = {0.f,0.f,0.f,0.f};
        {
            const int row = lane & 15;
            const char* base = (const char*)hA + row * 2048;
            #pragma unroll
            for (int kb = 0; kb < 32; kb += 2) {
                int cgA = kb * 4 + kg;
                short8 a0 = *(const short8*)(base + (((unsigned)(cgA       ^ (row & 7))) << 4));
                short8 a1 = *(const short8*)(base + (((unsigned)((cgA + 4) ^ (row & 7))) << 4));
                acc0 = __builtin_amdgcn_mfma_f32_16x16x32_bf16(a0, bfr[kb],     acc0, 0, 0, 0);
                acc1 = __builtin_amdgcn_mfma_f32_16x16x32_bf16(a1, bfr[kb + 1], acc1, 0, 0, 0);
            }
            #pragma unroll
            for (int r = 0; r < 4; ++r) acc0[r] += acc1[r];
        }
        if (kg < 2) {
            #pragma unroll
            for (int r = 0; r < 4; ++r)
                sgate[q][hu][kg * 4 + r][col] = acc0[r];
        }
        __syncthreads();
        // ---- pointwise: 256 threads = (batch n 0..7, unit j 0..31) ----
        if (tid < 256) {
            int n = tid >> 5, j = tid & 31;
            int ng = G * 8 + n, jg = l * 32 + j;
            float iv = sgate[0][j >> 4][n][j & 15] + h2f(xi)  + sbias[0][j];
            float fv = sgate[1][j >> 4][n][j & 15] + h2f(xf)  + sbias[1][j];
            float gv = sgate[2][j >> 4][n][j & 15] + h2f(xgv) + sbias[2][j];
            float ov = sgate[3][j >> 4][n][j & 15] + h2f(xo)  + sbias[3][j];
            iv = 1.f / (1.f + __expf(-iv));
            fv = 1.f / (1.f + __expf(-fv));
            ov = 1.f / (1.f + __expf(-ov));
            float eg = __expf(2.f * gv);
            gv = 1.f - 2.f / (eg + 1.f);
            creg = fv * creg + iv * gv;
            float ec = __expf(2.f * creg);
            float hh = ov * (1.f - 2.f / (ec + 1.f));
            y[((size_t)ng << 19) + ((size_t)t << 10) + jg] = hh;
            unsigned short hb = f2bf(hh);
            if (s == TCH - 1) {
                hcan[((size_t)ng << 10) + jg] = hb;    // plain: next launch / output state
                cws[((size_t)ng << 10) + jg] = creg;
            } else {
                unsigned int wv = (((nonce6 << 10) | ((unsigned)(t + 1) & 1023u)) << 16)
                                  | (unsigned int)hb;
                unsigned int* hp = (((t + 1) & 1) ? hxb1 : hxb0) + n * 1024 + jg;
                asm volatile("global_store_dword %0, %1, off sc0 sc1"
                             :: "v"(hp), "v"(wv) : "memory");
            }
        }
    }
}

extern "C" void kernel_launch(void* const* d_in, const int* in_sizes, int n_in,
                              void* d_out, int out_size, void* d_ws, size_t ws_size,
                              hipStream_t stream) {
    const float* x   = (const float*)d_in[0];
    const float* wih = (const float*)d_in[1];
    const float* whh = (const float*)d_in[2];
    const float* bih = (const float*)d_in[3];
    const float* bhh = (const float*)d_in[4];
    float* y = (float*)d_out;

    char* ws = (char*)d_ws;
    unsigned short* Whh_bf = (unsigned short*)ws;                           // 8 MiB
    unsigned short* Wih_bf = (unsigned short*)(ws + ((size_t)8 << 20));     // 8 MiB
    unsigned short* xgc    = (unsigned short*)(ws + ((size_t)16 << 20));    // 64 MiB (f16)
    char* SB               = ws + ((size_t)80 << 20);
    float* biasc           = (float*)SB;                                    // 16 KiB
    char* zb               = SB + (16u << 10);
    unsigned short* hcan   = (unsigned short*)zb;                           // 128 KiB
    float* cws             = (float*)(zb + (128u << 10));                   // 256 KiB
    unsigned int* hx       = (unsigned int*)(zb + (384u << 10));            // 512 KiB
    unsigned int* nonce    = (unsigned int*)(zb + (896u << 10));            // 4 B (NOT zeroed)
    const int nz = (896 << 10) / 4;
    if (ws_size < ((size_t)81 << 20)) return;

    hipLaunchKernelGGL(cvt_mat, dim3(2048), dim3(256), 0, stream, whh, Whh_bf, G4 * HID / 8);
    hipLaunchKernelGGL(cvt_mat, dim3(2048), dim3(256), 0, stream, wih, Wih_bf, G4 * HID / 8);
    hipLaunchKernelGGL(init_kernel, dim3(896), dim3(256), 0, stream,
                       bih, bhh, biasc, (unsigned int*)zb, nz, nonce);

    for (int chk = 0; chk < NCH; ++chk) {
        int t0 = chk * TCH;
        hipLaunchKernelGGL(xg_gemm, dim3(2048), dim3(256), 0, stream, x, Wih_bf, xgc, t0);
        void* args[] = {(void*)&Whh_bf, (void*)&xgc, (void*)&biasc, (void*)&hcan,
                        (void*)&hx, (void*)&cws, (void*)&nonce, (void*)&y, (void*)&t0};
        hipLaunchCooperativeKernel((const void*)lstm_persist, dim3(NWG), dim3(512),
                                   args, 0, stream);
    }
}